// Round 10
// baseline (246.521 us; speedup 1.0000x reference)
//
#include <hip/hip_runtime.h>

#define NLINKS 4096
#define CHUNKS 4          // fvec4 per thread: 4 * 4 * 256 threads = 4096 elems

typedef float fvec4 __attribute__((ext_vector_type(4)));

constexpr float kPmax = 0.1f;
constexpr float kBudget = 100.0f;
constexpr int kGrid = 5;          // tau grid points evaluated in pass A
constexpr float kBmax = 16.0f;    // constant upper bracket: g(16)=0 always
constexpr int kFallbackIters = 8; // Illinois iters when tau is outside grid

// clip(x,0,PMAX) in ONE VALU op: v_med3_f32
__device__ __forceinline__ float clip01(float x) {
  return __builtin_amdgcn_fmed3f(x, 0.0f, kPmax);
}

// Batched reduce: N independent sums share interleaved shuffle latency.
template <int N>
__device__ __forceinline__ void waveReduceSumN(float* x) {
#pragma unroll
  for (int m = 32; m >= 1; m >>= 1) {
    float t[N];
#pragma unroll
    for (int k = 0; k < N; ++k) t[k] = __shfl_xor(x[k], m, 64);
#pragma unroll
    for (int k = 0; k < N; ++k) x[k] += t[k];
  }
}

// ROUNDS 0-9 LESSON LEDGER (all falsified as the bottleneck):
//  r1/r2: register pressure (dbuf always spills at 128-VGPR cap)
//  r3/r4: wait placement (counted vmcnt: no change)
//  r6:    occupancy (3x more waves: no change)
//  r8:    VALU volume (-35% pass-A ops: no change)
//  r9:    load-latency exposure (verified in-flight prefetch: no change)
//  Kernel pinned at ~72-75 us = 3.7 TB/s on 268 MB vs 42.6 us copy floor.
//  Surviving theory: the HETEROGENEOUS PHASE STRUCTURE itself — every block
//  alternates load-burst / reduce+barrier / solve / store, all resident
//  blocks in the same cadence, so HBM demand is bursty and never pipelines.
//  THIS ROUND: split into two homogeneous kernels.
//   K1 (tau): row-per-block reduce+solve ONLY; caching reads (populate L3,
//       134 MB < 256 MB L3); writes 1 float/row to d_ws. tau=0 encodes the
//       feasible/clip-only rows so K2 is a single uniform formula.
//   K2 (apply): out = med3(raw - tau[row], 0, Pmax). Copy-shaped, zero
//       barriers/reduces, grid-stride; input re-read is L3-absorbed
//       (measured: r6 FETCH=149 MB for ~2.2 input passes); nt stores.
//  Same tau math, same final op => absmax unchanged.

__global__ __launch_bounds__(256) void tau_kernel(
    const float* __restrict__ raw, float* __restrict__ tau_out, int rows) {
  const int row = blockIdx.x;
  if (row >= rows) return;
  const int tid = threadIdx.x;
  const int wave = tid >> 6;
  const int lane = tid & 63;

  __shared__ float ldsA[4][kGrid + 1];  // pass A partials per wave
  __shared__ float ldsF[4];             // fallback g (rare)
  __shared__ float ldsN[4][2];          // Newton partials

  const fvec4* rp = (const fvec4*)(raw + (size_t)row * NLINKS);

  // CACHING loads (not nontemporal): we WANT the input resident in L2/L3
  // for the apply kernel's re-read.
  fvec4 v[CHUNKS];
#pragma unroll
  for (int j = 0; j < CHUNKS; ++j) v[j] = rp[tid + 256 * j];

  // tau ~= 0.641 +- 0.02 for this problem's N(0,1) rows; points span +-5
  // sigma. Outside -> Illinois fallback (correct, ~never taken).
  const float pts[kGrid] = {0.54f, 0.60f, 0.65f, 0.70f, 0.76f};

  // ---- Pass A: g(0)=fs and g(pts[i]) ----
  float s[kGrid + 1];
#pragma unroll
  for (int k = 0; k <= kGrid; ++k) s[k] = 0.f;
#pragma unroll
  for (int j = 0; j < CHUNKS; ++j) {
#pragma unroll
    for (int c = 0; c < 4; ++c) {
      const float x = v[j][c];
      s[0] += clip01(x);
#pragma unroll
      for (int i = 0; i < kGrid; ++i) s[i + 1] += clip01(x - pts[i]);
    }
  }
  waveReduceSumN<kGrid + 1>(s);
  if (lane == 0) {
#pragma unroll
    for (int k = 0; k <= kGrid; ++k) ldsA[wave][k] = s[k];
  }
  __syncthreads();
#pragma unroll
  for (int k = 0; k <= kGrid; ++k)
    s[k] = (ldsA[0][k] + ldsA[1][k]) + (ldsA[2][k] + ldsA[3][k]);
  const float fs = s[0];

  if (fs <= kBudget) {  // feasible: apply reduces to clip(raw-0, 0, Pmax)
    if (tid == 0) tau_out[row] = 0.f;
    return;
  }

  // Select bracketing segment. g is decreasing: g(0)=fs>B, g(kBmax)=0.
  float a = 0.f, ga = fs, b = kBmax, gb = 0.f;
  bool need_iter = true;
  if (s[1] < kBudget) {                    // tau < pts[0]
    a = 0.f; ga = fs; b = pts[0]; gb = s[1];
  } else if (s[kGrid] > kBudget) {         // tau > pts[last]
    a = pts[kGrid - 1]; ga = s[kGrid]; b = kBmax; gb = 0.f;
  } else {
#pragma unroll
    for (int i = 0; i < kGrid - 1; ++i) {
      if (s[i + 1] >= kBudget && s[i + 2] <= kBudget) {
        a = pts[i]; ga = s[i + 1]; b = pts[i + 1]; gb = s[i + 2];
        need_iter = false;
        break;
      }
    }
  }

  if (need_iter) {  // rare: Illinois false position on [a,b] (block-uniform)
    int side = 0;
#pragma unroll 1
    for (int it = 0; it < kFallbackIters; ++it) {
      const float denom = gb - ga;
      float t = (denom != 0.f) ? b - (gb - kBudget) * (b - a) / denom
                               : 0.5f * (a + b);
      if (!(t > a && t < b)) t = 0.5f * (a + b);
      float s0 = 0.f, s1 = 0.f, s2 = 0.f, s3 = 0.f;
#pragma unroll
      for (int j = 0; j < CHUNKS; ++j) {
        s0 += clip01(v[j].x - t);
        s1 += clip01(v[j].y - t);
        s2 += clip01(v[j].z - t);
        s3 += clip01(v[j].w - t);
      }
      float g = (s0 + s1) + (s2 + s3);
      waveReduceSumN<1>(&g);
      if (lane == 0) ldsF[wave] = g;
      __syncthreads();
      g = (ldsF[0] + ldsF[1]) + (ldsF[2] + ldsF[3]);
      __syncthreads();  // ldsF rewritten next iteration
      if (g > kBudget) {
        a = t; ga = g;
        if (side == 1) gb = kBudget + 0.5f * (gb - kBudget);
        side = 1;
      } else {
        b = t; gb = g;
        if (side == -1) ga = kBudget + 0.5f * (ga - kBudget);
        side = -1;
      }
    }
  }

  // False position within the (locally linear) segment.
  const float dd = ga - gb;
  float tau0 = (dd != 0.f) ? a + (ga - kBudget) * (b - a) / dd : 0.5f * (a + b);
  if (!(tau0 >= a && tau0 <= b)) tau0 = 0.5f * (a + b);

  // ---- Pass B: Newton correction (exact within the linear segment) ----
  float gn[2] = {0.f, 0.f};  // gn[0]=g(tau0), gn[1]=n_active
#pragma unroll
  for (int j = 0; j < CHUNKS; ++j) {
#pragma unroll
    for (int c = 0; c < 4; ++c) {
      const float t = v[j][c] - tau0;
      gn[0] += clip01(t);
      gn[1] += (t > 0.f && t < kPmax) ? 1.f : 0.f;
    }
  }
  waveReduceSumN<2>(gn);
  if (lane == 0) {
    ldsN[wave][0] = gn[0];
    ldsN[wave][1] = gn[1];
  }
  __syncthreads();
  gn[0] = (ldsN[0][0] + ldsN[1][0]) + (ldsN[2][0] + ldsN[3][0]);
  gn[1] = (ldsN[0][1] + ldsN[1][1]) + (ldsN[2][1] + ldsN[3][1]);
  const float tau = tau0 + (gn[0] - kBudget) / fmaxf(gn[1], 1.0f);

  if (tid == 0) tau_out[row] = tau;
}

// K2: pure streaming apply — structurally a copy with 2 extra VALU ops.
// Grid-stride over rows (2048 blocks x 4 rows: block turnover + no cohort
// lock). tau[row] is block-uniform -> compiler emits a scalar load.
__global__ __launch_bounds__(256) void apply_kernel(
    const float* __restrict__ raw, const float* __restrict__ tau_arr,
    float* __restrict__ out, int rows) {
  const int tid = threadIdx.x;
  for (int row = blockIdx.x; row < rows; row += gridDim.x) {
    const float tau = tau_arr[row];
    const fvec4* rp = (const fvec4*)(raw + (size_t)row * NLINKS);
    fvec4* op = (fvec4*)(out + (size_t)row * NLINKS);
#pragma unroll
    for (int j = 0; j < CHUNKS; ++j) {
      const fvec4 x = rp[tid + 256 * j];  // L3 hit (resident from K1)
      fvec4 o;
#pragma unroll
      for (int c = 0; c < 4; ++c) o[c] = clip01(x[c] - tau);
      __builtin_nontemporal_store(o, &op[tid + 256 * j]);
    }
  }
}

extern "C" void kernel_launch(void* const* d_in, const int* in_sizes, int n_in,
                              void* d_out, int out_size, void* d_ws, size_t ws_size,
                              hipStream_t stream) {
  const float* raw = (const float*)d_in[0];
  float* out = (float*)d_out;
  const int rows = in_sizes[0] / NLINKS;
  float* tau_arr = (float*)d_ws;  // rows*4 B = 32 KB (ws is far larger)

  // K1: one row per block — reduce+solve only, writes tau[row].
  hipLaunchKernelGGL(tau_kernel, dim3(rows), dim3(256), 0, stream,
                     raw, tau_arr, rows);
  // K2: copy-shaped apply, grid-stride with turnover.
  int blocks = rows < 2048 ? rows : 2048;
  hipLaunchKernelGGL(apply_kernel, dim3(blocks), dim3(256), 0, stream,
                     raw, tau_arr, out, rows);
}

// Round 11
// 228.610 us; speedup vs baseline: 1.0783x; 1.0783x over previous
//
#include <hip/hip_runtime.h>

#define NLINKS 4096
#define CHUNKS 4          // fvec4 per thread: 4 * 4 * 256 threads = 4096 elems

typedef float fvec4 __attribute__((ext_vector_type(4)));

constexpr float kPmax = 0.1f;
constexpr float kBudget = 100.0f;
constexpr int kGrid = 5;          // tau grid points evaluated in pass A
constexpr float kBmax = 16.0f;    // constant upper bracket: g(16)=0 always
constexpr int kFallbackIters = 8; // Illinois iters when tau is outside grid

// clip(x,0,PMAX) in ONE VALU op: v_med3_f32
__device__ __forceinline__ float clip01(float x) {
  return __builtin_amdgcn_fmed3f(x, 0.0f, kPmax);
}

// Batched reduce: N independent sums share interleaved shuffle latency.
template <int N>
__device__ __forceinline__ void waveReduceSumN(float* x) {
#pragma unroll
  for (int m = 32; m >= 1; m >>= 1) {
    float t[N];
#pragma unroll
    for (int k = 0; k < N; ++k) t[k] = __shfl_xor(x[k], m, 64);
#pragma unroll
    for (int k = 0; k < N; ++k) x[k] += t[k];
  }
}

// ROUNDS 0-10 LESSON LEDGER (all falsified as the bottleneck):
//  r1/r2: register pressure (dbuf always spills at 128-VGPR cap)
//  r3/r4: wait placement (counted vmcnt: no change)
//  r6:    occupancy (3x more waves: no change)
//  r8:    VALU volume (-35% pass-A ops: no change)
//  r9:    load-latency exposure (verified in-flight prefetch: no change)
//  r10:   phase heterogeneity (two homogeneous kernels: WORSE, split costs
//         ~25 us; reverted)
//  Every variant 70-94 us at ~3.8 TB/s vs the 6.3 TB/s plain-float4 copy.
//  THIS ROUND: the one variable every variant shared and never tested —
//  ALL of them bypassed the caches (nontemporal loads AND stores, inherited
//  from round 0). Mechanism: (1) harness fills rewrite ~537 MiB between
//  iterations, leaving input pages L2/L3-warm; NT loads set the bypass bits
//  and forfeit those hits, paying full HBM latency/BW on every row. (2) NT
//  stores put HBM on the completion path; plain stores complete at L2-ack
//  and write back after retirement — exactly how the fill posts 6.8 TB/s.
//  The proven-fast kernels here (fill, m13 copy 6.29 TB/s) use PLAIN
//  accesses. This kernel is byte-identical to r8 except NT -> plain.
__global__ __launch_bounds__(256) void proj_kernel(
    const float* __restrict__ raw, float* __restrict__ out, int rows) {
  const int row = blockIdx.x;
  if (row >= rows) return;
  const int tid = threadIdx.x;
  const int wave = tid >> 6;
  const int lane = tid & 63;

  // Site-private LDS so reduce sites can't race each other.
  __shared__ float ldsA[4][kGrid + 1];  // pass A: s[0..kGrid]
  __shared__ float ldsF[4];             // fallback g (rewritten per iter)
  __shared__ float ldsN[4][2];          // Newton: g(tau0), n_active

  const fvec4* rp = (const fvec4*)(raw + (size_t)row * NLINKS);
  fvec4* op = (fvec4*)(out + (size_t)row * NLINKS);

  // Whole row in block registers: 4 fvec4/thread = 16 VGPRs, coalesced.
  // PLAIN loads: take the L2/L3 hits the harness leaves warm.
  fvec4 v[CHUNKS];
#pragma unroll
  for (int j = 0; j < CHUNKS; ++j) v[j] = rp[tid + 256 * j];

  // tau ~= 0.641 +- 0.02 (sigma across rows) for this problem's N(0,1)
  // inputs; points span +-5 sigma. Outside -> Illinois fallback (correct).
  const float pts[kGrid] = {0.54f, 0.60f, 0.65f, 0.70f, 0.76f};

  // ---- Pass A: g(0)=fs and g(pts[i]) for all grid points ----
  float s[kGrid + 1];
#pragma unroll
  for (int k = 0; k <= kGrid; ++k) s[k] = 0.f;
#pragma unroll
  for (int j = 0; j < CHUNKS; ++j) {
#pragma unroll
    for (int c = 0; c < 4; ++c) {
      const float x = v[j][c];
      s[0] += clip01(x);
#pragma unroll
      for (int i = 0; i < kGrid; ++i) s[i + 1] += clip01(x - pts[i]);
    }
  }
  waveReduceSumN<kGrid + 1>(s);
  if (lane == 0) {
#pragma unroll
    for (int k = 0; k <= kGrid; ++k) ldsA[wave][k] = s[k];
  }
  __syncthreads();
#pragma unroll
  for (int k = 0; k <= kGrid; ++k)
    s[k] = (ldsA[0][k] + ldsA[1][k]) + (ldsA[2][k] + ldsA[3][k]);
  const float fs = s[0];

  if (fs <= kBudget) {  // feasible: clip only (block-uniform branch)
#pragma unroll
    for (int j = 0; j < CHUNKS; ++j) {
      fvec4 o;
#pragma unroll
      for (int c = 0; c < 4; ++c) o[c] = clip01(v[j][c]);
      op[tid + 256 * j] = o;  // plain store: complete at L2-ack
    }
    return;
  }

  // Select bracketing segment. g is decreasing: g(0)=fs>B, g(kBmax)=0.
  float a = 0.f, ga = fs, b = kBmax, gb = 0.f;
  bool need_iter = true;
  if (s[1] < kBudget) {                    // tau < pts[0]: Illinois refines
    a = 0.f; ga = fs; b = pts[0]; gb = s[1];
  } else if (s[kGrid] > kBudget) {         // tau > pts[last]: Illinois refines
    a = pts[kGrid - 1]; ga = s[kGrid]; b = kBmax; gb = 0.f;
  } else {
#pragma unroll
    for (int i = 0; i < kGrid - 1; ++i) {
      if (s[i + 1] >= kBudget && s[i + 2] <= kBudget) {
        a = pts[i]; ga = s[i + 1]; b = pts[i + 1]; gb = s[i + 2];
        need_iter = false;
        break;
      }
    }
  }

  if (need_iter) {  // rare: Illinois false position on [a,b] (block-uniform)
    int side = 0;
#pragma unroll 1
    for (int it = 0; it < kFallbackIters; ++it) {
      const float denom = gb - ga;
      float t = (denom != 0.f) ? b - (gb - kBudget) * (b - a) / denom
                               : 0.5f * (a + b);
      if (!(t > a && t < b)) t = 0.5f * (a + b);
      float s0 = 0.f, s1 = 0.f, s2 = 0.f, s3 = 0.f;
#pragma unroll
      for (int j = 0; j < CHUNKS; ++j) {
        s0 += clip01(v[j].x - t);
        s1 += clip01(v[j].y - t);
        s2 += clip01(v[j].z - t);
        s3 += clip01(v[j].w - t);
      }
      float g = (s0 + s1) + (s2 + s3);
      waveReduceSumN<1>(&g);
      if (lane == 0) ldsF[wave] = g;
      __syncthreads();
      g = (ldsF[0] + ldsF[1]) + (ldsF[2] + ldsF[3]);
      __syncthreads();  // ldsF rewritten next iteration
      if (g > kBudget) {
        a = t; ga = g;
        if (side == 1) gb = kBudget + 0.5f * (gb - kBudget);
        side = 1;
      } else {
        b = t; gb = g;
        if (side == -1) ga = kBudget + 0.5f * (ga - kBudget);
        side = -1;
      }
    }
  }

  // False position within the (locally linear) segment.
  const float dd = ga - gb;
  float tau0 = (dd != 0.f) ? a + (ga - kBudget) * (b - a) / dd : 0.5f * (a + b);
  if (!(tau0 >= a && tau0 <= b)) tau0 = 0.5f * (a + b);

  // ---- Pass B: Newton correction (exact within the linear segment) ----
  float gn[2] = {0.f, 0.f};  // gn[0]=g(tau0), gn[1]=n_active
#pragma unroll
  for (int j = 0; j < CHUNKS; ++j) {
#pragma unroll
    for (int c = 0; c < 4; ++c) {
      const float t = v[j][c] - tau0;
      gn[0] += clip01(t);
      gn[1] += (t > 0.f && t < kPmax) ? 1.f : 0.f;
    }
  }
  waveReduceSumN<2>(gn);
  if (lane == 0) {
    ldsN[wave][0] = gn[0];
    ldsN[wave][1] = gn[1];
  }
  __syncthreads();
  gn[0] = (ldsN[0][0] + ldsN[1][0]) + (ldsN[2][0] + ldsN[3][0]);
  gn[1] = (ldsN[0][1] + ldsN[1][1]) + (ldsN[2][1] + ldsN[3][1]);
  const float tau = tau0 + (gn[0] - kBudget) / fmaxf(gn[1], 1.0f);

  // ---- Pass C: output from registers (plain stores) ----
#pragma unroll
  for (int j = 0; j < CHUNKS; ++j) {
    fvec4 o;
#pragma unroll
    for (int c = 0; c < 4; ++c) o[c] = clip01(v[j][c] - tau);
    op[tid + 256 * j] = o;
  }
}

extern "C" void kernel_launch(void* const* d_in, const int* in_sizes, int n_in,
                              void* d_out, int out_size, void* d_ws, size_t ws_size,
                              hipStream_t stream) {
  const float* raw = (const float*)d_in[0];
  float* out = (float*)d_out;
  const int rows = in_sizes[0] / NLINKS;
  // One row per block: 8192 independent blocks, short per-row critical path.
  hipLaunchKernelGGL(proj_kernel, dim3(rows), dim3(256), 0, stream,
                     raw, out, rows);
}